// Round 2
// baseline (5252.868 us; speedup 1.0000x reference)
//
#include <hip/hip_runtime.h>
#include <hip/hip_bf16.h>

#define NSTEPS 10
#define DT     0.1f
#define LNEPS  1e-5f
#define NLOG2E (-1.4426950408889634f)
#define SH     520   // hbuf row stride (ushort): 512 + 8 pad, rows 16B-aligned
#define SR     40    // Rchunk row stride (ushort): 32 + 8 pad, conflict-free

typedef __attribute__((ext_vector_type(8))) short v8s;   // 8 bf16 MFMA operand
typedef __attribute__((ext_vector_type(4))) float v4f;   // 4 fp32 MFMA accum

static __device__ __forceinline__ ushort f2bf(float f) {
  union { float f; unsigned u; } v; v.f = f;
  unsigned r = v.u + 0x7fffu + ((v.u >> 16) & 1u);   // RNE
  return (ushort)(r >> 16);
}
static __device__ __forceinline__ float bfl(unsigned u) {
  union { unsigned x; float f; } c; c.x = u << 16; return c.f;
}
static __device__ __forceinline__ float bfh(unsigned u) {
  union { unsigned x; float f; } c; c.x = u & 0xffff0000u; return c.f;
}
static __device__ __forceinline__ unsigned pk2(float a, float b) {
  union { __hip_bfloat162 h; unsigned u; } c;
  c.h = __float22bfloat162_rn(make_float2(a, b));   // lowers to v_cvt_pk_bf16_f32
  return c.u;
}

// ---------------------------------------------------------------------------
// Pack weights into MFMA B-fragment order (verified R1), with scale folding.
// B[k][n], k = kc*32 + (lane>>4)*8 + j, n = ctg*16 + (lane&15);
// frag f = (kc*NT + ctg)*64 + lane, 8 bf16 (16B) each.
// ---------------------------------------------------------------------------
__global__ void pack_w(const float* __restrict__ src, const float* __restrict__ msk,
                       ushort* __restrict__ dst, int K, int N, int trans, float scale) {
  int nt = N >> 4;
  int tot = (K >> 5) * nt * 64;
  int f = blockIdx.x * blockDim.x + threadIdx.x;
  if (f >= tot) return;
  int flane = f & 63;
  int rest = f >> 6;
  int ctg = rest % nt;
  int kc = rest / nt;
  int n = ctg * 16 + (flane & 15);
  int kb = kc * 32 + ((flane >> 4) & 3) * 8;
  ushort v[8];
#pragma unroll
  for (int j = 0; j < 8; ++j) {
    int k = kb + j;
    float s;
    if (trans) {
      s = src[(size_t)n * K + k];
      if (msk) s *= msk[(size_t)n * K + k];
    } else {
      s = src[(size_t)k * N + n];
    }
    v[j] = f2bf(s * scale);
  }
  uint4 u;
  u.x = (unsigned)v[0] | ((unsigned)v[1] << 16);
  u.y = (unsigned)v[2] | ((unsigned)v[3] << 16);
  u.z = (unsigned)v[4] | ((unsigned)v[5] << 16);
  u.w = (unsigned)v[6] | ((unsigned)v[7] << 16);
  *(uint4*)(dst + (size_t)f * 8) = u;
}

// Per-layer per-col constants, f32: u1 = {dt*A, 1+dt/tau}, u2 = {g, b}.
__global__ void pack_consts(const float* __restrict__ tau, const float* __restrict__ A,
                            const float* __restrict__ g, const float* __restrict__ b,
                            float2* __restrict__ u1, float2* __restrict__ u2) {
  int c = blockIdx.x * blockDim.x + threadIdx.x;
  if (c >= 512) return;
  u1[c] = make_float2(DT * A[c], 1.f + DT / tau[c]);
  u2[c] = make_float2(g[c], b[c]);
}

struct LayerG {
  const ushort* win;
  const ushort* wrec;
  const float*  bias;   // raw f32, scaled by -log2e at use
  const float2* u1;     // {ac, c1}
  const float2* u2;     // {g, b}
  int kcw;              // K/32 for the input GEMM (8 for layer 0, else 16)
};
struct KP {
  const float* x;
  LayerG L[3];
  const ushort* wout;
  const float*  outb;
  float* out;
};

// ---------------------------------------------------------------------------
// Wave-independent fused kernel: each wave owns 16 batch rows end-to-end.
// 256 thr = 4 waves/block; NO __syncthreads anywhere (all LDS is wave-private,
// ordered by in-wave lgkmcnt). h state lives in per-wave LDS in MFMA-A layout;
// the per-step C->A transform goes through a 32-col ping-pong chunk.
// ---------------------------------------------------------------------------
__global__ __launch_bounds__(256, 2) void liquid_fused(KP P) {
  extern __shared__ char smem[];
  const int tid = threadIdx.x;
  const int w = tid >> 6, lane = tid & 63;
  const int q = lane >> 4, m = lane & 15;
  ushort* hb = (ushort*)smem + w * (16 * SH);                       // 16 x 512 bf16, A layout
  ushort* rb = (ushort*)(smem + 4 * 16 * SH * 2) + w * (2 * 16 * SR); // ping-pong chunk
  const int row0 = blockIdx.x * 64 + w * 16;

  // ---- stage x (16 rows x 256 f32 -> bf16, row-major = A layout)
  {
    const float4* x4 = (const float4*)P.x;
#pragma unroll
    for (int r = 0; r < 16; ++r) {
      float4 v = x4[(size_t)(row0 + r) * 64 + lane];
      uint2 o; o.x = pk2(v.x, v.y); o.y = pk2(v.z, v.w);
      *(uint2*)(hb + r * SH + lane * 4) = o;
    }
  }

  v4f acc[32];     // GEMM accum (C layout) -> recycled as h_new (A layout)
  uint4 bb[16];    // base' = -log2e*(i_input + bias), bf16-packed, A layout

#pragma unroll 1
  for (int l = 0; l < 3; ++l) {
    const LayerG L = P.L[l];

    // ---- i_input' GEMM: acc = hb @ win'  (win pre-scaled by -log2e)
    {
#pragma unroll
      for (int ct = 0; ct < 32; ++ct) acc[ct] = (v4f){0.f, 0.f, 0.f, 0.f};
      for (int kc = 0; kc < L.kcw; ++kc) {
        v8s a = *(const v8s*)(hb + m * SH + kc * 32 + q * 8);
#pragma unroll
        for (int ct = 0; ct < 32; ++ct) {
          v8s b = *(const v8s*)(L.win + ((size_t)(kc * 32 + ct) * 64 + lane) * 8);
          acc[ct] = __builtin_amdgcn_mfma_f32_16x16x32_bf16(a, b, acc[ct], 0, 0, 0);
        }
      }
    }
    // ---- base build: transpose C->A through rb, add scaled bias, pack into bb
#pragma unroll
    for (int kc = 0; kc < 16; ++kc) {
      ushort* rc = rb + (kc & 1) * (16 * SR);
#pragma unroll
      for (int t = 0; t < 2; ++t)
#pragma unroll
        for (int r = 0; r < 4; ++r)
          rc[(4 * q + r) * SR + 16 * t + m] = f2bf(acc[2 * kc + t][r]);
      uint4 rr = *(const uint4*)(rc + m * SR + 8 * q);
      const float4* bp = (const float4*)(L.bias + kc * 32 + q * 8);
      float4 b0 = bp[0], b1 = bp[1];
      uint4 o;
      o.x = pk2(fmaf(NLOG2E, b0.x, bfl(rr.x)), fmaf(NLOG2E, b0.y, bfh(rr.x)));
      o.y = pk2(fmaf(NLOG2E, b0.z, bfl(rr.y)), fmaf(NLOG2E, b0.w, bfh(rr.y)));
      o.z = pk2(fmaf(NLOG2E, b1.x, bfl(rr.z)), fmaf(NLOG2E, b1.y, bfh(rr.z)));
      o.w = pk2(fmaf(NLOG2E, b1.z, bfl(rr.w)), fmaf(NLOG2E, b1.w, bfh(rr.w)));
      bb[kc] = o;
    }

    // ---- 10 semi-implicit ODE steps, no barriers
#pragma unroll 1
    for (int s = 0; s < NSTEPS; ++s) {
      const bool rec = (s > 0);
      if (rec) {
#pragma unroll
        for (int ct = 0; ct < 32; ++ct) acc[ct] = (v4f){0.f, 0.f, 0.f, 0.f};
        for (int kc = 0; kc < 16; ++kc) {
          v8s a = *(const v8s*)(hb + m * SH + kc * 32 + q * 8);
#pragma unroll
          for (int ct = 0; ct < 32; ++ct) {
            v8s b = *(const v8s*)(L.wrec + ((size_t)(kc * 32 + ct) * 64 + lane) * 8);
            acc[ct] = __builtin_amdgcn_mfma_f32_16x16x32_bf16(a, b, acc[ct], 0, 0, 0);
          }
        }
        // prime chunk 0
#pragma unroll
        for (int t = 0; t < 2; ++t)
#pragma unroll
          for (int r = 0; r < 4; ++r)
            rb[(4 * q + r) * SR + 16 * t + m] = f2bf(acc[t][r]);
      }
      float S = 0.f, S2 = 0.f;
      // ---- pass 1: per 32-col chunk, transpose rec, fuse sigmoid+update (A layout)
#pragma unroll
      for (int kc = 0; kc < 16; ++kc) {
        if (rec && kc < 15) {   // write next chunk (ping-pong)
          ushort* rc = rb + ((kc + 1) & 1) * (16 * SR);
#pragma unroll
          for (int t = 0; t < 2; ++t)
#pragma unroll
            for (int r = 0; r < 4; ++r)
              rc[(4 * q + r) * SR + 16 * t + m] = f2bf(acc[2 * (kc + 1) + t][r]);
        }
        uint4 rr = make_uint4(0, 0, 0, 0), hh = make_uint4(0, 0, 0, 0);
        if (rec) {
          rr = *(const uint4*)(rb + (kc & 1) * (16 * SR) + m * SR + 8 * q);
          hh = *(const uint4*)(hb + m * SH + kc * 32 + 8 * q);   // hold = h_prev
        }
        const float4* cp = (const float4*)(L.u1 + (kc * 32 + 8 * q));
        float4 u0 = cp[0], u1v = cp[1], u2v = cp[2], u3v = cp[3];
        float cs[16] = {u0.x, u0.y, u0.z, u0.w, u1v.x, u1v.y, u1v.z, u1v.w,
                        u2v.x, u2v.y, u2v.z, u2v.w, u3v.x, u3v.y, u3v.z, u3v.w};
        unsigned rw[4] = {rr.x, rr.y, rr.z, rr.w};
        unsigned hw[4] = {hh.x, hh.y, hh.z, hh.w};
        unsigned bw[4] = {bb[kc].x, bb[kc].y, bb[kc].z, bb[kc].w};
#pragma unroll
        for (int j = 0; j < 8; ++j) {
          unsigned rd = rw[j >> 1], hd = hw[j >> 1], bd = bw[j >> 1];
          float rv = (j & 1) ? bfh(rd) : bfl(rd);
          float hv = (j & 1) ? bfh(hd) : bfl(hd);
          float bv = (j & 1) ? bfh(bd) : bfl(bd);
          float ac_ = cs[2 * j], c1_ = cs[2 * j + 1];
          // e = exp(-(arg)); arg' pre-scaled by -log2e in weights/base
          float e = exp2f(rv + bv);
          // h_new = (hold + ac*f)/(c1 + dt*f), f=1/(1+e)  -> Mobius by (1+e):
          float num = fmaf(hv, e, hv + ac_);
          float den = fmaf(c1_, e, c1_ + DT);
          float hn = num * __builtin_amdgcn_rcpf(den);
          S += hn; S2 = fmaf(hn, hn, S2);
          acc[2 * kc + (j >> 2)][j & 3] = hn;   // recycle acc as h_new (A layout)
        }
      }
      // ---- LN stats: one row per lane -> 4 shuffles total
      S  += __shfl_xor(S, 16);  S  += __shfl_xor(S, 32);
      S2 += __shfl_xor(S2, 16); S2 += __shfl_xor(S2, 32);
      float mu = S * (1.f / 512.f);
      float var = fmaf(-mu, mu, S2 * (1.f / 512.f));
      float rs = __builtin_amdgcn_rsqf(var + LNEPS);
      float nm = -mu * rs;
      // ---- pass 2: normalize + affine, pack bf16, b128 write to hb (A layout)
#pragma unroll
      for (int kc = 0; kc < 16; ++kc) {
        const float4* gp = (const float4*)(L.u2 + (kc * 32 + 8 * q));
        float4 g0 = gp[0], g1 = gp[1], g2 = gp[2], g3 = gp[3];
        float gs[16] = {g0.x, g0.y, g0.z, g0.w, g1.x, g1.y, g1.z, g1.w,
                        g2.x, g2.y, g2.z, g2.w, g3.x, g3.y, g3.z, g3.w};
        float vv[8];
#pragma unroll
        for (int j = 0; j < 8; ++j) {
          float hn = acc[2 * kc + (j >> 2)][j & 3];
          float t = fmaf(hn, rs, nm);
          vv[j] = fmaf(t, gs[2 * j], gs[2 * j + 1]);
        }
        uint4 o;
        o.x = pk2(vv[0], vv[1]); o.y = pk2(vv[2], vv[3]);
        o.z = pk2(vv[4], vv[5]); o.w = pk2(vv[6], vv[7]);
        *(uint4*)(hb + m * SH + kc * 32 + 8 * q) = o;
      }
    }
  }

  // ---- output projection: out = h @ out_W^T + out_b (N=128)
  v4f oa[8];
#pragma unroll
  for (int ct = 0; ct < 8; ++ct) oa[ct] = (v4f){0.f, 0.f, 0.f, 0.f};
  for (int kc = 0; kc < 16; ++kc) {
    v8s a = *(const v8s*)(hb + m * SH + kc * 32 + q * 8);
#pragma unroll
    for (int ct = 0; ct < 8; ++ct) {
      v8s b = *(const v8s*)(P.wout + ((size_t)(kc * 8 + ct) * 64 + lane) * 8);
      oa[ct] = __builtin_amdgcn_mfma_f32_16x16x32_bf16(a, b, oa[ct], 0, 0, 0);
    }
  }
#pragma unroll
  for (int ct = 0; ct < 8; ++ct) {
    float ob = P.outb[ct * 16 + m];
#pragma unroll
    for (int r = 0; r < 4; ++r)
      P.out[(size_t)(row0 + 4 * q + r) * 128 + ct * 16 + m] = oa[ct][r] + ob;
  }
}

// ---------------------------------------------------------------------------
extern "C" void kernel_launch(void* const* d_in, const int* in_sizes, int n_in,
                              void* d_out, int out_size, void* d_ws, size_t ws_size,
                              hipStream_t stream) {
  (void)in_sizes; (void)n_in; (void)out_size; (void)ws_size;
  ushort* ws = (ushort*)d_ws;

  const size_t S_WIN0 = 0;
  const size_t S_WIN1 = S_WIN0 + (size_t)8 * 32 * 64 * 8;
  const size_t S_WIN2 = S_WIN1 + (size_t)16 * 32 * 64 * 8;
  const size_t S_REC0 = S_WIN2 + (size_t)16 * 32 * 64 * 8;
  const size_t S_REC1 = S_REC0 + (size_t)16 * 32 * 64 * 8;
  const size_t S_REC2 = S_REC1 + (size_t)16 * 32 * 64 * 8;
  const size_t S_WOUT = S_REC2 + (size_t)16 * 32 * 64 * 8;
  const size_t CONST_B = (S_WOUT + (size_t)16 * 8 * 64 * 8) * 2;  // byte offset

  const float* f[27];
  for (int i = 0; i < 27; ++i) f[i] = (const float*)d_in[i];

  dim3 bt(256);
  pack_w<<<dim3(64),  bt, 0, stream>>>(f[1],  nullptr, ws + S_WIN0, 256, 512, 0, NLOG2E);
  pack_w<<<dim3(128), bt, 0, stream>>>(f[9],  nullptr, ws + S_WIN1, 512, 512, 0, NLOG2E);
  pack_w<<<dim3(128), bt, 0, stream>>>(f[17], nullptr, ws + S_WIN2, 512, 512, 0, NLOG2E);
  pack_w<<<dim3(128), bt, 0, stream>>>(f[2],  f[6],    ws + S_REC0, 512, 512, 1, NLOG2E);
  pack_w<<<dim3(128), bt, 0, stream>>>(f[10], f[14],   ws + S_REC1, 512, 512, 1, NLOG2E);
  pack_w<<<dim3(128), bt, 0, stream>>>(f[18], f[22],   ws + S_REC2, 512, 512, 1, NLOG2E);
  pack_w<<<dim3(32),  bt, 0, stream>>>(f[25], nullptr, ws + S_WOUT, 512, 128, 1, 1.0f);

  float2* u1 = (float2*)((char*)d_ws + CONST_B);
  float2* u2 = u1 + 3 * 512;
  for (int l = 0; l < 3; ++l) {
    int b0 = 1 + 8 * l;
    pack_consts<<<dim3(2), bt, 0, stream>>>(f[b0 + 3], f[b0 + 4], f[b0 + 6], f[b0 + 7],
                                            u1 + l * 512, u2 + l * 512);
  }

  KP P;
  P.x = f[0];
  const size_t win_off[3] = {S_WIN0, S_WIN1, S_WIN2};
  const size_t rec_off[3] = {S_REC0, S_REC1, S_REC2};
  for (int l = 0; l < 3; ++l) {
    int b0 = 1 + 8 * l;
    P.L[l].win  = ws + win_off[l];
    P.L[l].wrec = ws + rec_off[l];
    P.L[l].bias = f[b0 + 2];
    P.L[l].u1   = u1 + l * 512;
    P.L[l].u2   = u2 + l * 512;
    P.L[l].kcw  = (l == 0) ? 8 : 16;
  }
  P.wout = ws + S_WOUT;
  P.outb = f[26];
  P.out  = (float*)d_out;

  const int smem = 4 * 16 * SH * 2 + 4 * 2 * 16 * SR * 2;  // 76800 B -> 2 blocks/CU
  hipFuncSetAttribute((const void*)liquid_fused,
                      hipFuncAttributeMaxDynamicSharedMemorySize, smem);
  liquid_fused<<<dim3(512), dim3(256), smem, stream>>>(P);
}

// Round 3
// 1499.270 us; speedup vs baseline: 3.5036x; 3.5036x over previous
//
#include <hip/hip_runtime.h>
#include <hip/hip_bf16.h>

#define NSTEPS 10
#define DT     0.1f
#define LNEPS  1e-5f
#define NLOG2E (-1.4426950408889634f)
#define SH     520   // hb row stride (ushort): 512 + 8 pad; rows 16B-aligned
#define BR     128   // rows per block (one block per CU)

typedef __attribute__((ext_vector_type(8))) short v8s;   // 8 bf16 MFMA operand
typedef __attribute__((ext_vector_type(4))) float v4f;   // 4 fp32 MFMA accum

static __device__ __forceinline__ ushort f2bf(float f) {
  union { float f; unsigned u; } v; v.f = f;
  unsigned r = v.u + 0x7fffu + ((v.u >> 16) & 1u);   // RNE
  return (ushort)(r >> 16);
}
static __device__ __forceinline__ float bfbits(unsigned hw) {  // low 16 bits = bf16
  union { unsigned u; float f; } v; v.u = hw << 16; return v.f;
}
static __device__ __forceinline__ float bfl(unsigned u) {
  union { unsigned x; float f; } c; c.x = u << 16; return c.f;
}
static __device__ __forceinline__ float bfh(unsigned u) {
  union { unsigned x; float f; } c; c.x = u & 0xffff0000u; return c.f;
}
static __device__ __forceinline__ unsigned pk2(float a, float b) {
  union { __hip_bfloat162 h; unsigned u; } c;
  c.h = __float22bfloat162_rn(make_float2(a, b));   // v_cvt_pk_bf16_f32
  return c.u;
}

// ---------------------------------------------------------------------------
// Pack weights into MFMA B-fragment order (verified R1/R2), w/ scale folding.
// B[k][n], k = kc*32 + (lane>>4)*8 + j, n = ctg*16 + (lane&15);
// frag f = (kc*NT + ctg)*64 + lane, 8 bf16 (16B) each.
// ---------------------------------------------------------------------------
__global__ void pack_w(const float* __restrict__ src, const float* __restrict__ msk,
                       ushort* __restrict__ dst, int K, int N, int trans, float scale) {
  int nt = N >> 4;
  int tot = (K >> 5) * nt * 64;
  int f = blockIdx.x * blockDim.x + threadIdx.x;
  if (f >= tot) return;
  int flane = f & 63;
  int rest = f >> 6;
  int ctg = rest % nt;
  int kc = rest / nt;
  int n = ctg * 16 + (flane & 15);
  int kb = kc * 32 + ((flane >> 4) & 3) * 8;
  ushort v[8];
#pragma unroll
  for (int j = 0; j < 8; ++j) {
    int k = kb + j;
    float s;
    if (trans) {
      s = src[(size_t)n * K + k];
      if (msk) s *= msk[(size_t)n * K + k];
    } else {
      s = src[(size_t)k * N + n];
    }
    v[j] = f2bf(s * scale);
  }
  uint4 u;
  u.x = (unsigned)v[0] | ((unsigned)v[1] << 16);
  u.y = (unsigned)v[2] | ((unsigned)v[3] << 16);
  u.z = (unsigned)v[4] | ((unsigned)v[5] << 16);
  u.w = (unsigned)v[6] | ((unsigned)v[7] << 16);
  *(uint4*)(dst + (size_t)f * 8) = u;
}

// Per-layer per-col constants, f32: u1 = {dt*A, 1+dt/tau}, u2 = {g, b}.
__global__ void pack_consts(const float* __restrict__ tau, const float* __restrict__ A,
                            const float* __restrict__ g, const float* __restrict__ b,
                            float2* __restrict__ u1, float2* __restrict__ u2) {
  int c = blockIdx.x * blockDim.x + threadIdx.x;
  if (c >= 512) return;
  u1[c] = make_float2(DT * A[c], 1.f + DT / tau[c]);
  u2[c] = make_float2(g[c], b[c]);
}

struct LayerG {
  const ushort* win;
  const ushort* wrec;
  const float*  bias;   // raw f32, scaled by -log2e at base build
  const float2* u1;     // {ac, c1}
  const float2* u2;     // {g, b}
};
struct KP {
  const float* x;
  LayerG L[3];
  const ushort* wout;
  const float*  outb;
  float* out;
};

// ---------------------------------------------------------------------------
// Column-slab GEMM: acc[8][4] += hb(128 x 32*KC bf16, LDS) @ Wpacked.
// Wave wv owns cols [64*wv, 64*wv+64). 1-deep B prefetch from global (L2).
// A-frag: row = rt*16 + (lane&15), k = kc*32 + (lane>>4)*8 + j (ds_read_b128).
// C/D: row = rt*16 + (lane>>4)*4 + r, col = wv*64 + ct*16 + (lane&15).
// ---------------------------------------------------------------------------
template <int KC>
static __device__ __forceinline__ void gemm_cs(const ushort* hb, const ushort* __restrict__ w,
                                               int wv, int lane, int q, int m,
                                               v4f (&acc)[8][4]) {
#pragma unroll
  for (int rt = 0; rt < 8; ++rt)
#pragma unroll
    for (int ct = 0; ct < 4; ++ct) acc[rt][ct] = (v4f){0.f, 0.f, 0.f, 0.f};
  v8s bc[4];
#pragma unroll
  for (int ct = 0; ct < 4; ++ct)
    bc[ct] = *(const v8s*)(w + ((size_t)(wv * 4 + ct) * 64 + lane) * 8);
  for (int kc = 0; kc < KC; ++kc) {
    v8s bn[4];
    if (kc + 1 < KC) {
#pragma unroll
      for (int ct = 0; ct < 4; ++ct)
        bn[ct] = *(const v8s*)(w + ((size_t)((kc + 1) * 32 + wv * 4 + ct) * 64 + lane) * 8);
    }
#pragma unroll
    for (int rt = 0; rt < 8; ++rt) {
      v8s a = *(const v8s*)(hb + (rt * 16 + m) * SH + kc * 32 + q * 8);
#pragma unroll
      for (int ct = 0; ct < 4; ++ct)
        acc[rt][ct] = __builtin_amdgcn_mfma_f32_16x16x32_bf16(a, bc[ct], acc[rt][ct], 0, 0, 0);
    }
    if (kc + 1 < KC) {
#pragma unroll
      for (int ct = 0; ct < 4; ++ct) bc[ct] = bn[ct];
    }
  }
}

// ---------------------------------------------------------------------------
// Fused kernel: 1 block/CU, 128 rows, 8 waves (col-slab), 3 layers x 10 steps.
// h state in LDS bf16 (A layout). 3 barriers/step (GEMM | stats | writeback).
// ---------------------------------------------------------------------------
__global__ __launch_bounds__(512, 2) void liquid_fused(KP P) {
  extern __shared__ char smem[];
  ushort* hb = (ushort*)smem;                          // [BR][SH] bf16 h (A layout)
  float2* stats  = (float2*)(smem + BR * SH * 2);      // [BR][8] per-wave (S, S2)
  float2* stats2 = stats + BR * 8;                     // [BR] (mu, rsig)

  const int tid = threadIdx.x;
  const int wv = tid >> 6, lane = tid & 63;
  const int q = lane >> 4, m = lane & 15;
  const int row0 = blockIdx.x * BR;
  const int wc0 = wv * 64;

  // ---- stage x: 128 rows x 256 f32 -> bf16 (row-major = A layout)
  {
    const float4* x4 = (const float4*)P.x;
#pragma unroll
    for (int i = 0; i < 16; ++i) {
      int fi = i * 512 + tid;            // 0..8191
      int r = fi >> 6, c4 = fi & 63;
      float4 v = x4[(size_t)(row0 + r) * 64 + c4];
      uint2 o; o.x = pk2(v.x, v.y); o.y = pk2(v.z, v.w);
      *(uint2*)(hb + r * SH + c4 * 4) = o;
    }
  }
  __syncthreads();

  v4f acc[8][4];        // GEMM accum (C layout), recycled as h_new scratch
  uint2 basep[8][4];    // base' = -log2e*(i_input + bias), packed bf16

#pragma unroll 1
  for (int l = 0; l < 3; ++l) {
    const LayerG L = P.L[l];

    // ---- i_input' GEMM (win pre-scaled by -log2e) + base pack
    if (l == 0) gemm_cs<8>(hb, L.win, wv, lane, q, m, acc);
    else        gemm_cs<16>(hb, L.win, wv, lane, q, m, acc);
#pragma unroll
    for (int ct = 0; ct < 4; ++ct) {
      float bs = NLOG2E * L.bias[wc0 + ct * 16 + m];
#pragma unroll
      for (int rt = 0; rt < 8; ++rt) {
        basep[rt][ct].x = pk2(acc[rt][ct][0] + bs, acc[rt][ct][1] + bs);
        basep[rt][ct].y = pk2(acc[rt][ct][2] + bs, acc[rt][ct][3] + bs);
      }
    }

#pragma unroll 1
    for (int s = 0; s < NSTEPS; ++s) {
      if (s > 0) gemm_cs<16>(hb, L.wrec, wv, lane, q, m, acc);  // h @ (W_rec*mask)'

      // ---- per-step consts (transient; not live across the GEMM)
      float ac[4], c1[4], c1d[4];
#pragma unroll
      for (int ct = 0; ct < 4; ++ct) {
        float2 u = L.u1[wc0 + ct * 16 + m];
        ac[ct] = u.x; c1[ct] = u.y; c1d[ct] = u.y + DT;
      }

      // ---- pass 1: sigmoid + semi-implicit update + per-rt stats reduce
#pragma unroll
      for (int rt = 0; rt < 8; ++rt) {
        float S[4] = {0.f, 0.f, 0.f, 0.f}, S2[4] = {0.f, 0.f, 0.f, 0.f};
#pragma unroll
        for (int ct = 0; ct < 4; ++ct) {
          unsigned blo = basep[rt][ct].x, bhi = basep[rt][ct].y;
#pragma unroll
          for (int r = 0; r < 4; ++r) {
            float bv = (r == 0) ? bfl(blo) : (r == 1) ? bfh(blo)
                     : (r == 2) ? bfl(bhi) : bfh(bhi);
            float arg = bv;
            float hv = 0.f;
            if (s > 0) {
              arg += acc[rt][ct][r];
              hv = bfbits(hb[(rt * 16 + q * 4 + r) * SH + wc0 + ct * 16 + m]);
            }
            float e = exp2f(arg);                       // = exp(-raw_arg)
            float num = fmaf(hv, e, hv + ac[ct]);       // Mobius x(1+e)
            float den = fmaf(c1[ct], e, c1d[ct]);
            float hn = num * __builtin_amdgcn_rcpf(den);
            S[r] += hn; S2[r] = fmaf(hn, hn, S2[r]);
            acc[rt][ct][r] = hn;
          }
        }
#pragma unroll
        for (int msk = 1; msk <= 8; msk <<= 1)
#pragma unroll
          for (int r = 0; r < 4; ++r) {
            S[r]  += __shfl_xor(S[r],  msk);
            S2[r] += __shfl_xor(S2[r], msk);
          }
        if (m == 0) {
#pragma unroll
          for (int r = 0; r < 4; ++r)
            stats[(rt * 16 + q * 4 + r) * 8 + wv] = make_float2(S[r], S2[r]);
        }
      }
      __syncthreads();
      if (tid < BR) {
        float S = 0.f, S2 = 0.f;
#pragma unroll
        for (int i = 0; i < 8; ++i) { float2 t = stats[tid * 8 + i]; S += t.x; S2 += t.y; }
        float mu = S * (1.f / 512.f);
        float var = fmaf(-mu, mu, S2 * (1.f / 512.f));
        stats2[tid] = make_float2(mu, __builtin_amdgcn_rsqf(var + LNEPS));
      }
      __syncthreads();

      // ---- pass 2: normalize + affine, write bf16 h back to hb
      float gg[4], gb[4];
#pragma unroll
      for (int ct = 0; ct < 4; ++ct) {
        float2 u = L.u2[wc0 + ct * 16 + m];
        gg[ct] = u.x; gb[ct] = u.y;
      }
#pragma unroll
      for (int rt = 0; rt < 8; ++rt) {
        float rs[4], nm[4];
#pragma unroll
        for (int r = 0; r < 4; ++r) {
          float2 t = stats2[rt * 16 + q * 4 + r];
          rs[r] = t.y; nm[r] = -t.x * t.y;
        }
#pragma unroll
        for (int ct = 0; ct < 4; ++ct) {
#pragma unroll
          for (int rp = 0; rp < 2; ++rp) {
            float v0 = fmaf(fmaf(acc[rt][ct][2 * rp],     rs[2 * rp],     nm[2 * rp]),     gg[ct], gb[ct]);
            float v1 = fmaf(fmaf(acc[rt][ct][2 * rp + 1], rs[2 * rp + 1], nm[2 * rp + 1]), gg[ct], gb[ct]);
            unsigned pk = pk2(v0, v1);
            hb[(rt * 16 + q * 4 + 2 * rp)     * SH + wc0 + ct * 16 + m] = (ushort)(pk & 0xffffu);
            hb[(rt * 16 + q * 4 + 2 * rp + 1) * SH + wc0 + ct * 16 + m] = (ushort)(pk >> 16);
          }
        }
      }
      __syncthreads();
    }
  }

  // ---- output projection: out = h @ out_W^T + out_b (N=128; wave owns 16 cols)
  v4f oa[8];
#pragma unroll
  for (int rt = 0; rt < 8; ++rt) oa[rt] = (v4f){0.f, 0.f, 0.f, 0.f};
  v8s bcur = *(const v8s*)(P.wout + ((size_t)wv * 64 + lane) * 8);
  for (int kc = 0; kc < 16; ++kc) {
    v8s bnxt;
    if (kc + 1 < 16)
      bnxt = *(const v8s*)(P.wout + ((size_t)((kc + 1) * 8 + wv) * 64 + lane) * 8);
#pragma unroll
    for (int rt = 0; rt < 8; ++rt) {
      v8s a = *(const v8s*)(hb + (rt * 16 + m) * SH + kc * 32 + q * 8);
      oa[rt] = __builtin_amdgcn_mfma_f32_16x16x32_bf16(a, bcur, oa[rt], 0, 0, 0);
    }
    if (kc + 1 < 16) bcur = bnxt;
  }
  {
    float ob = P.outb[wv * 16 + m];
#pragma unroll
    for (int rt = 0; rt < 8; ++rt)
#pragma unroll
      for (int r = 0; r < 4; ++r)
        P.out[(size_t)(row0 + rt * 16 + q * 4 + r) * 128 + wv * 16 + m] = oa[rt][r] + ob;
  }
}

// ---------------------------------------------------------------------------
extern "C" void kernel_launch(void* const* d_in, const int* in_sizes, int n_in,
                              void* d_out, int out_size, void* d_ws, size_t ws_size,
                              hipStream_t stream) {
  (void)in_sizes; (void)n_in; (void)out_size; (void)ws_size;
  ushort* ws = (ushort*)d_ws;

  const size_t S_WIN0 = 0;
  const size_t S_WIN1 = S_WIN0 + (size_t)8 * 32 * 64 * 8;
  const size_t S_WIN2 = S_WIN1 + (size_t)16 * 32 * 64 * 8;
  const size_t S_REC0 = S_WIN2 + (size_t)16 * 32 * 64 * 8;
  const size_t S_REC1 = S_REC0 + (size_t)16 * 32 * 64 * 8;
  const size_t S_REC2 = S_REC1 + (size_t)16 * 32 * 64 * 8;
  const size_t S_WOUT = S_REC2 + (size_t)16 * 32 * 64 * 8;
  const size_t CONST_B = (S_WOUT + (size_t)16 * 8 * 64 * 8) * 2;  // byte offset

  const float* f[27];
  for (int i = 0; i < 27; ++i) f[i] = (const float*)d_in[i];

  dim3 bt(256);
  pack_w<<<dim3(64),  bt, 0, stream>>>(f[1],  nullptr, ws + S_WIN0, 256, 512, 0, NLOG2E);
  pack_w<<<dim3(128), bt, 0, stream>>>(f[9],  nullptr, ws + S_WIN1, 512, 512, 0, NLOG2E);
  pack_w<<<dim3(128), bt, 0, stream>>>(f[17], nullptr, ws + S_WIN2, 512, 512, 0, NLOG2E);
  pack_w<<<dim3(128), bt, 0, stream>>>(f[2],  f[6],    ws + S_REC0, 512, 512, 1, NLOG2E);
  pack_w<<<dim3(128), bt, 0, stream>>>(f[10], f[14],   ws + S_REC1, 512, 512, 1, NLOG2E);
  pack_w<<<dim3(128), bt, 0, stream>>>(f[18], f[22],   ws + S_REC2, 512, 512, 1, NLOG2E);
  pack_w<<<dim3(32),  bt, 0, stream>>>(f[25], nullptr, ws + S_WOUT, 512, 128, 1, 1.0f);

  float2* u1 = (float2*)((char*)d_ws + CONST_B);
  float2* u2 = u1 + 3 * 512;
  for (int l = 0; l < 3; ++l) {
    int b0 = 1 + 8 * l;
    pack_consts<<<dim3(2), bt, 0, stream>>>(f[b0 + 3], f[b0 + 4], f[b0 + 6], f[b0 + 7],
                                            u1 + l * 512, u2 + l * 512);
  }

  KP P;
  P.x = f[0];
  const size_t win_off[3] = {S_WIN0, S_WIN1, S_WIN2};
  const size_t rec_off[3] = {S_REC0, S_REC1, S_REC2};
  for (int l = 0; l < 3; ++l) {
    int b0 = 1 + 8 * l;
    P.L[l].win  = ws + win_off[l];
    P.L[l].wrec = ws + rec_off[l];
    P.L[l].bias = f[b0 + 2];
    P.L[l].u1   = u1 + l * 512;
    P.L[l].u2   = u2 + l * 512;
  }
  P.wout = ws + S_WOUT;
  P.outb = f[26];
  P.out  = (float*)d_out;

  const int smem = BR * SH * 2 + BR * 8 * 8 + BR * 8;  // 142336 B -> 1 block/CU
  hipFuncSetAttribute((const void*)liquid_fused,
                      hipFuncAttributeMaxDynamicSharedMemorySize, smem);
  liquid_fused<<<dim3(32768 / BR), dim3(512), smem, stream>>>(P);
}